// Round 4
// baseline (405.130 us; speedup 1.0000x reference)
//
#include <hip/hip_runtime.h>

typedef unsigned short u16;
typedef unsigned int u32;
typedef short bf16x8 __attribute__((ext_vector_type(8)));
typedef float f32x4 __attribute__((ext_vector_type(4)));

#define Ndim 2048    // H (= N of GEMM)
#define Kdim 1024    // D (= K of GEMM)
#define Lseq 2048
#define NT   16      // Kdim / 64

__device__ __forceinline__ void gload_lds16(const void* g, void* l) {
    __builtin_amdgcn_global_load_lds(
        (const __attribute__((address_space(1))) u32*)(g),
        (__attribute__((address_space(3))) u32*)(l), 16, 0, 0);
}

__device__ __forceinline__ u16 f32_to_bf16(float f) {
    u32 u = __builtin_bit_cast(u32, f);
    u += 0x7FFFu + ((u >> 16) & 1u);
    return (u16)(u >> 16);
}

// 2-bit XOR swizzle for [*][128 rows][32 k] bf16 LDS (row stride 64B):
// bank-quad bits 4,5 get row bits 2,3 (addr bits 8,9); bit6 already = row bit 0.
// 16-lane ds_read_b128 groups spread over all 8 bank-quads -> ~2-way (free).
// Involution (bits 8,9 untouched); applied to BOTH gload-source and ds_read addr.
__device__ __forceinline__ u32 swz(u32 x) {
    return x ^ (((x >> 9) & 1u) << 5) ^ (((x >> 8) & 1u) << 4);
}

// ---------------- cast f32 -> bf16, 8 elems/thread ----------------
__global__ __launch_bounds__(256) void cast_f32_bf16(
        const float* __restrict__ in, u16* __restrict__ out, int n8) {
    int i = blockIdx.x * 256 + threadIdx.x;
    if (i >= n8) return;
    const float4* p = (const float4*)(in + (size_t)i * 8);
    float4 a = p[0], b = p[1];
    float v[8] = {a.x, a.y, a.z, a.w, b.x, b.y, b.z, b.w};
    u32 o[4];
#pragma unroll
    for (int j = 0; j < 4; ++j) {
        u32 lo = f32_to_bf16(v[2 * j]);
        u32 hi = f32_to_bf16(v[2 * j + 1]);
        o[j] = lo | (hi << 16);
    }
    uint4 ov = make_uint4(o[0], o[1], o[2], o[3]);
    *(uint4*)(out + (size_t)i * 8) = ov;
}

// ---------------- tap sums ----------------
__global__ __launch_bounds__(256) void taps_kernel(
        const float* __restrict__ mem_w, const float* __restrict__ la_w,
        float* __restrict__ cw) {
    int k = blockIdx.x;
    if (k == 50) {
        if (threadIdx.x == 0) cw[50] = 1.0f;
        return;
    }
    const float* src = (k < 50) ? (mem_w + (size_t)k * Ndim)
                                : (la_w + (size_t)(k - 51) * Ndim);
    float s = 0.f;
    for (int i = threadIdx.x; i < Ndim; i += 256) s += src[i];
#pragma unroll
    for (int off = 32; off; off >>= 1) s += __shfl_down(s, off);
    __shared__ float part[4];
    if ((threadIdx.x & 63) == 0) part[threadIdx.x >> 6] = s;
    __syncthreads();
    if (threadIdx.x == 0) cw[k] = part[0] + part[1] + part[2] + part[3];
}

// ---------------- GEMM: 256x256 tile, BK=64, 8 waves, 8-phase schedule ----------------
// LDS half-tile layout: [ks:2][row:128][k:32] bf16 (8KB per ks), swizzled via swz().
// Phase/staging/vmcnt schedule identical to round 3 (race-free; vmcnt(4) counted).
__global__ __launch_bounds__(512, 1) void gemm8(
        const u16* __restrict__ A, const u16* __restrict__ Bw,
        const float* __restrict__ bias, u16* __restrict__ C) {
    __shared__ __align__(16) u16 smem[65536];   // 128 KiB
    char* sb = (char*)smem;

    const int tid = threadIdx.x;
    const int w = tid >> 6, lane = tid & 63;
    const int ln = lane & 15, kq = lane >> 4;
    const int wr = w >> 2, wc = w & 3;

    // XCD-aware bijective swizzle (512 blocks, 8 XCDs)
    const int id0 = blockIdx.x;
    const int id = (id0 & 7) * 64 + (id0 >> 3);
    const int bm = id >> 3, bn = id & 7;

    const u32 aoff = (u32)(wr * 64 + ln) * 64 + (u32)kq * 16;
    const u32 boff = (u32)(wc * 32 + ln) * 64 + (u32)kq * 16;

    f32x4 acc[8][4] = {};

    auto stage = [&](int kt2, int which) {
        const int ah = which & 1;
        const bool isB = (which >> 1) != 0;
        const u16* src = isB ? Bw : A;
        const int rowbase = (isB ? bn * 256 : bm * 256) + ah * 128;
        const u32 dbase = (u32)(kt2 & 1) * 65536u + (isB ? 32768u : 0u) + (u32)ah * 16384u;
#pragma unroll
        for (int p = 0; p < 2; ++p) {
            u32 off = (u32)(p * 512 + tid) * 16;
            u32 soff = swz(off);                     // involution: source pre-swizzle
            u32 ks  = off >> 13;                     // bits 13+ unaffected by swz
            u32 row = (off >> 6) & 127u;             // bits 6..12: bit 8,9 read via off==soff
            u32 kc  = (soff & 63u) >> 1;
            gload_lds16(src + (size_t)(rowbase + (int)row) * Kdim + kt2 * 64 + (int)(ks * 32u + kc),
                        sb + dbase + off);           // linear LDS dest
        }
    };

    // prologue: tile0 all 4 halves + tile1 {A0, B0}
    stage(0, 0); stage(0, 1); stage(0, 2); stage(0, 3);
    stage(1, 0); stage(1, 2);
    asm volatile("s_waitcnt vmcnt(4)");
    __builtin_amdgcn_sched_barrier(0);
    __builtin_amdgcn_s_barrier();

    for (int kt = 0; kt < NT; ++kt) {
        const u32 bufb = (u32)(kt & 1) * 65536u;
#pragma unroll
        for (int q = 0; q < 4; ++q) {
            const int mh = q >> 1, nh = q & 1;
            bf16x8 a[4][2], b[2][2];
#pragma unroll
            for (int m = 0; m < 4; ++m)
#pragma unroll
                for (int ks = 0; ks < 2; ++ks)
                    a[m][ks] = *(const bf16x8*)(sb + bufb + (u32)mh * 16384u +
                                                swz(aoff + (u32)m * 1024u + (u32)ks * 8192u));
#pragma unroll
            for (int n = 0; n < 2; ++n)
#pragma unroll
                for (int ks = 0; ks < 2; ++ks)
                    b[n][ks] = *(const bf16x8*)(sb + bufb + 32768u + (u32)nh * 16384u +
                                                swz(boff + (u32)n * 1024u + (u32)ks * 8192u));
            if (q == 0)      { if (kt + 1 < NT) stage(kt + 1, 1); }
            else if (q == 1) { if (kt + 1 < NT) stage(kt + 1, 3); }
            else if (q == 2) { if (kt + 2 < NT) stage(kt + 2, 0); }
            else             { if (kt + 2 < NT) stage(kt + 2, 2); }
            __builtin_amdgcn_s_barrier();
            asm volatile("s_waitcnt lgkmcnt(0)");
            __builtin_amdgcn_sched_barrier(0);
            __builtin_amdgcn_s_setprio(1);
#pragma unroll
            for (int m = 0; m < 4; ++m)
#pragma unroll
                for (int n = 0; n < 2; ++n) {
                    acc[mh * 4 + m][nh * 2 + n] = __builtin_amdgcn_mfma_f32_16x16x32_bf16(
                        a[m][0], b[n][0], acc[mh * 4 + m][nh * 2 + n], 0, 0, 0);
                    acc[mh * 4 + m][nh * 2 + n] = __builtin_amdgcn_mfma_f32_16x16x32_bf16(
                        a[m][1], b[n][1], acc[mh * 4 + m][nh * 2 + n], 0, 0, 0);
                }
            __builtin_amdgcn_s_setprio(0);
            if (q == 3) {
                asm volatile("s_waitcnt vmcnt(4)");   // counted, never 0 in the loop
                __builtin_amdgcn_sched_barrier(0);
            }
            __builtin_amdgcn_s_barrier();
        }
    }

    // epilogue: bias add, cvt bf16, store
    const int colbase = bn * 256 + wc * 32;
    const int rowbase = bm * 256 + wr * 64;
#pragma unroll
    for (int nh = 0; nh < 2; ++nh)
#pragma unroll
        for (int n = 0; n < 2; ++n) {
            int col = colbase + nh * 128 + n * 16 + ln;
            float bv = bias[col];
#pragma unroll
            for (int mh = 0; mh < 2; ++mh)
#pragma unroll
                for (int m = 0; m < 4; ++m) {
                    int row0 = rowbase + mh * 128 + m * 16 + kq * 4;
                    f32x4 v = acc[mh * 4 + m][nh * 2 + n];
#pragma unroll
                    for (int r = 0; r < 4; ++r)
                        C[(size_t)(row0 + r) * Ndim + col] = f32_to_bf16(v[r] + bv);
                }
        }
}

// ---------------- fused banded-conv + LayerNorm ----------------
// Block: 16 t x full H, 512 threads; thread: 4 ch x 16 t (64 f32 acc).
// XCD-chunked block swizzle: XCD k owns batch k's t-range in order -> window
// overlap (55/71 rows) hits same-XCD L2.
__global__ __launch_bounds__(512) void conv_ln(
        const u16* __restrict__ h, const float* __restrict__ cwg,
        const float* __restrict__ gamma, const float* __restrict__ beta,
        float* __restrict__ out) {
    const int tid = threadIdx.x;
    const int id0 = (blockIdx.y << 7) + blockIdx.x;      // gridDim = (128, 8)
    const int id = (id0 & 7) * 128 + (id0 >> 3);         // bijective (1024 % 8 == 0)
    const int b = id >> 7;
    const int tb = (id & 127) * 16;

    __shared__ float scw[86];          // scw[i] = cw[i-15], zero-padded; valid i in [15,71)
    __shared__ float red[8][16][2];
    if (tid < 86) scw[tid] = (tid >= 15 && tid < 71) ? cwg[tid - 15] : 0.f;
    __syncthreads();

    const u16* hb = h + (size_t)b * Lseq * Ndim;
    const int ch = tid * 4;
    float acc[16][4] = {};

    if (tb >= 50) {
        // fast path: rows r = tb-50 .. min(tb+20, L-1); weight(t2, lr) = scw[lr - t2 + 15]
        const int lrend = min(70, (Lseq - 1) - (tb - 50));
        const u16* rp = hb + (size_t)(tb - 50) * Ndim + ch;
        for (int lr = 0; lr <= lrend; ++lr) {
            uint2 u = *(const uint2*)rp;
            rp += Ndim;
            float hv[4];
            hv[0] = __builtin_bit_cast(float, u.x << 16);
            hv[1] = __builtin_bit_cast(float, u.x & 0xFFFF0000u);
            hv[2] = __builtin_bit_cast(float, u.y << 16);
            hv[3] = __builtin_bit_cast(float, u.y & 0xFFFF0000u);
#pragma unroll
            for (int t2 = 0; t2 < 16; ++t2) {
                float wgt = scw[lr - t2 + 15];
#pragma unroll
                for (int j = 0; j < 4; ++j)
                    acc[t2][j] = fmaf(wgt, hv[j], acc[t2][j]);
            }
        }
    } else {
        // slow path: tb in {0,16,32,48}; absolute-position mem taps for t<50
        const int rmax = tb + 20;
        const u16* rp = hb + ch;
        for (int r = 0; r <= rmax; ++r) {
            uint2 u = *(const uint2*)rp;
            rp += Ndim;
            float hv[4];
            hv[0] = __builtin_bit_cast(float, u.x << 16);
            hv[1] = __builtin_bit_cast(float, u.x & 0xFFFF0000u);
            hv[2] = __builtin_bit_cast(float, u.y << 16);
            hv[3] = __builtin_bit_cast(float, u.y & 0xFFFF0000u);
#pragma unroll
            for (int t2 = 0; t2 < 16; ++t2) {
                int t = tb + t2;
                float wgt;
                if (t >= 50) {
                    int wi = r - t + 50;
                    wgt = ((unsigned)wi <= 55u) ? scw[wi + 15] : 0.f;
                } else if (r < t) {
                    wgt = scw[r + 15];                 // wm[r], absolute-position taps
                } else {
                    int d = r - t;
                    wgt = (d <= 5) ? scw[50 + d + 15] : 0.f;  // self + future taps
                }
#pragma unroll
                for (int j = 0; j < 4; ++j)
                    acc[t2][j] = fmaf(wgt, hv[j], acc[t2][j]);
            }
        }
    }

    // LayerNorm over H=2048 per t
    float g[4], be[4];
    *(float4*)&g[0] = *(const float4*)(gamma + ch);
    *(float4*)&be[0] = *(const float4*)(beta + ch);

    float s1v[16], s2v[16];
#pragma unroll
    for (int t2 = 0; t2 < 16; ++t2) {
        float s1 = 0.f, s2 = 0.f;
#pragma unroll
        for (int j = 0; j < 4; ++j) {
            s1 += acc[t2][j];
            s2 += acc[t2][j] * acc[t2][j];
        }
        s1v[t2] = s1;
        s2v[t2] = s2;
    }
#pragma unroll
    for (int off = 32; off; off >>= 1) {
#pragma unroll
        for (int t2 = 0; t2 < 16; ++t2) {
            s1v[t2] += __shfl_down(s1v[t2], off);
            s2v[t2] += __shfl_down(s2v[t2], off);
        }
    }
    const int wv = tid >> 6, lane = tid & 63;
    if (lane == 0) {
#pragma unroll
        for (int t2 = 0; t2 < 16; ++t2) {
            red[wv][t2][0] = s1v[t2];
            red[wv][t2][1] = s2v[t2];
        }
    }
    __syncthreads();
    const float inv = 1.0f / (float)Ndim;
#pragma unroll
    for (int t2 = 0; t2 < 16; ++t2) {
        float S1 = 0.f, S2 = 0.f;
#pragma unroll
        for (int wv2 = 0; wv2 < 8; ++wv2) {
            S1 += red[wv2][t2][0];
            S2 += red[wv2][t2][1];
        }
        float mu = S1 * inv;
        float var = S2 * inv - mu * mu;
        float rs = rsqrtf(var + 1e-5f);
        size_t base = ((size_t)(b * Lseq + tb + t2)) * Ndim + ch;
        float4 o;
        o.x = (acc[t2][0] - mu) * rs * g[0] + be[0];
        o.y = (acc[t2][1] - mu) * rs * g[1] + be[1];
        o.z = (acc[t2][2] - mu) * rs * g[2] + be[2];
        o.w = (acc[t2][3] - mu) * rs * g[3] + be[3];
        *(float4*)(out + base) = o;
    }
}

extern "C" void kernel_launch(void* const* d_in, const int* in_sizes, int n_in,
                              void* d_out, int out_size, void* d_ws, size_t ws_size,
                              hipStream_t stream) {
    const float* x     = (const float*)d_in[0];  // [8,2048,1024]
    const float* W     = (const float*)d_in[1];  // [2048,1024]
    const float* b_lin = (const float*)d_in[2];  // [2048]
    const float* mem_w = (const float*)d_in[3];  // [50,2048]
    const float* la_w  = (const float*)d_in[4];  // [5,2048]
    const float* gamma = (const float*)d_in[5];  // [2048]
    const float* beta  = (const float*)d_in[6];  // [2048]
    float* out = (float*)d_out;

    u16* xb = (u16*)d_ws;                 // 16,777,216 bf16
    u16* wb = xb + (size_t)16777216;      //  2,097,152 bf16
    u16* hb = wb + (size_t)2097152;       // 33,554,432 bf16
    float* cw = (float*)(hb + (size_t)33554432);  // 56 f32

    taps_kernel<<<dim3(56), dim3(256), 0, stream>>>(mem_w, la_w, cw);
    cast_f32_bf16<<<dim3(8192), dim3(256), 0, stream>>>(x, xb, 2097152);
    cast_f32_bf16<<<dim3(1024), dim3(256), 0, stream>>>(W, wb, 262144);
    gemm8<<<dim3(512), dim3(512), 0, stream>>>(xb, wb, b_lin, hb);
    conv_ln<<<dim3(128, 8), dim3(512), 0, stream>>>(hb, cw, gamma, beta, out);
}

// Round 5
// 350.287 us; speedup vs baseline: 1.1566x; 1.1566x over previous
//
#include <hip/hip_runtime.h>

typedef unsigned short u16;
typedef unsigned int u32;
typedef short bf16x8 __attribute__((ext_vector_type(8)));
typedef float f32x4 __attribute__((ext_vector_type(4)));

#define Ndim 2048    // H (= N of GEMM)
#define Kdim 1024    // D (= K of GEMM)
#define Lseq 2048
#define NT   16      // Kdim / 64

__device__ __forceinline__ void gload_lds16(const void* g, void* l) {
    __builtin_amdgcn_global_load_lds(
        (const __attribute__((address_space(1))) u32*)(g),
        (__attribute__((address_space(3))) u32*)(l), 16, 0, 0);
}

__device__ __forceinline__ u16 f32_to_bf16(float f) {
    u32 u = __builtin_bit_cast(u32, f);
    u += 0x7FFFu + ((u >> 16) & 1u);
    return (u16)(u >> 16);
}

// 2-bit XOR swizzle for [*][128 rows][32 k] bf16 LDS (row stride 64B):
// bank-quad bits 4,5 get row bits 2,3 (addr bits 8,9); bit6 already = row bit 0.
// Involution (bits 8,9 untouched); applied to BOTH gload-source and ds_read addr.
__device__ __forceinline__ u32 swz(u32 x) {
    return x ^ (((x >> 9) & 1u) << 5) ^ (((x >> 8) & 1u) << 4);
}

// ---------------- cast f32 -> bf16, 8 elems/thread ----------------
__global__ __launch_bounds__(256) void cast_f32_bf16(
        const float* __restrict__ in, u16* __restrict__ out, int n8) {
    int i = blockIdx.x * 256 + threadIdx.x;
    if (i >= n8) return;
    const float4* p = (const float4*)(in + (size_t)i * 8);
    float4 a = p[0], b = p[1];
    float v[8] = {a.x, a.y, a.z, a.w, b.x, b.y, b.z, b.w};
    u32 o[4];
#pragma unroll
    for (int j = 0; j < 4; ++j) {
        u32 lo = f32_to_bf16(v[2 * j]);
        u32 hi = f32_to_bf16(v[2 * j + 1]);
        o[j] = lo | (hi << 16);
    }
    uint4 ov = make_uint4(o[0], o[1], o[2], o[3]);
    *(uint4*)(out + (size_t)i * 8) = ov;
}

// ---------------- tap sums ----------------
__global__ __launch_bounds__(256) void taps_kernel(
        const float* __restrict__ mem_w, const float* __restrict__ la_w,
        float* __restrict__ cw) {
    int k = blockIdx.x;
    if (k == 50) {
        if (threadIdx.x == 0) cw[50] = 1.0f;
        return;
    }
    const float* src = (k < 50) ? (mem_w + (size_t)k * Ndim)
                                : (la_w + (size_t)(k - 51) * Ndim);
    float s = 0.f;
    for (int i = threadIdx.x; i < Ndim; i += 256) s += src[i];
#pragma unroll
    for (int off = 32; off; off >>= 1) s += __shfl_down(s, off);
    __shared__ float part[4];
    if ((threadIdx.x & 63) == 0) part[threadIdx.x >> 6] = s;
    __syncthreads();
    if (threadIdx.x == 0) cw[k] = part[0] + part[1] + part[2] + part[3];
}

// ---------------- GEMM: 256x256 tile, BK=64, 8 waves, 8-phase (unchanged r4) ----------
__global__ __launch_bounds__(512, 1) void gemm8(
        const u16* __restrict__ A, const u16* __restrict__ Bw,
        const float* __restrict__ bias, u16* __restrict__ C) {
    __shared__ __align__(16) u16 smem[65536];   // 128 KiB
    char* sb = (char*)smem;

    const int tid = threadIdx.x;
    const int w = tid >> 6, lane = tid & 63;
    const int ln = lane & 15, kq = lane >> 4;
    const int wr = w >> 2, wc = w & 3;

    const int id0 = blockIdx.x;
    const int id = (id0 & 7) * 64 + (id0 >> 3);
    const int bm = id >> 3, bn = id & 7;

    const u32 aoff = (u32)(wr * 64 + ln) * 64 + (u32)kq * 16;
    const u32 boff = (u32)(wc * 32 + ln) * 64 + (u32)kq * 16;

    f32x4 acc[8][4] = {};

    auto stage = [&](int kt2, int which) {
        const int ah = which & 1;
        const bool isB = (which >> 1) != 0;
        const u16* src = isB ? Bw : A;
        const int rowbase = (isB ? bn * 256 : bm * 256) + ah * 128;
        const u32 dbase = (u32)(kt2 & 1) * 65536u + (isB ? 32768u : 0u) + (u32)ah * 16384u;
#pragma unroll
        for (int p = 0; p < 2; ++p) {
            u32 off = (u32)(p * 512 + tid) * 16;
            u32 soff = swz(off);
            u32 ks  = off >> 13;
            u32 row = (off >> 6) & 127u;
            u32 kc  = (soff & 63u) >> 1;
            gload_lds16(src + (size_t)(rowbase + (int)row) * Kdim + kt2 * 64 + (int)(ks * 32u + kc),
                        sb + dbase + off);
        }
    };

    stage(0, 0); stage(0, 1); stage(0, 2); stage(0, 3);
    stage(1, 0); stage(1, 2);
    asm volatile("s_waitcnt vmcnt(4)");
    __builtin_amdgcn_sched_barrier(0);
    __builtin_amdgcn_s_barrier();

    for (int kt = 0; kt < NT; ++kt) {
        const u32 bufb = (u32)(kt & 1) * 65536u;
#pragma unroll
        for (int q = 0; q < 4; ++q) {
            const int mh = q >> 1, nh = q & 1;
            bf16x8 a[4][2], b[2][2];
#pragma unroll
            for (int m = 0; m < 4; ++m)
#pragma unroll
                for (int ks = 0; ks < 2; ++ks)
                    a[m][ks] = *(const bf16x8*)(sb + bufb + (u32)mh * 16384u +
                                                swz(aoff + (u32)m * 1024u + (u32)ks * 8192u));
#pragma unroll
            for (int n = 0; n < 2; ++n)
#pragma unroll
                for (int ks = 0; ks < 2; ++ks)
                    b[n][ks] = *(const bf16x8*)(sb + bufb + 32768u + (u32)nh * 16384u +
                                                swz(boff + (u32)n * 1024u + (u32)ks * 8192u));
            if (q == 0)      { if (kt + 1 < NT) stage(kt + 1, 1); }
            else if (q == 1) { if (kt + 1 < NT) stage(kt + 1, 3); }
            else if (q == 2) { if (kt + 2 < NT) stage(kt + 2, 0); }
            else             { if (kt + 2 < NT) stage(kt + 2, 2); }
            __builtin_amdgcn_s_barrier();
            asm volatile("s_waitcnt lgkmcnt(0)");
            __builtin_amdgcn_sched_barrier(0);
            __builtin_amdgcn_s_setprio(1);
#pragma unroll
            for (int m = 0; m < 4; ++m)
#pragma unroll
                for (int n = 0; n < 2; ++n) {
                    acc[mh * 4 + m][nh * 2 + n] = __builtin_amdgcn_mfma_f32_16x16x32_bf16(
                        a[m][0], b[n][0], acc[mh * 4 + m][nh * 2 + n], 0, 0, 0);
                    acc[mh * 4 + m][nh * 2 + n] = __builtin_amdgcn_mfma_f32_16x16x32_bf16(
                        a[m][1], b[n][1], acc[mh * 4 + m][nh * 2 + n], 0, 0, 0);
                }
            __builtin_amdgcn_s_setprio(0);
            if (q == 3) {
                asm volatile("s_waitcnt vmcnt(4)");
                __builtin_amdgcn_sched_barrier(0);
            }
            __builtin_amdgcn_s_barrier();
        }
    }

    const int colbase = bn * 256 + wc * 32;
    const int rowbase = bm * 256 + wr * 64;
#pragma unroll
    for (int nh = 0; nh < 2; ++nh)
#pragma unroll
        for (int n = 0; n < 2; ++n) {
            int col = colbase + nh * 128 + n * 16 + ln;
            float bv = bias[col];
#pragma unroll
            for (int mh = 0; mh < 2; ++mh)
#pragma unroll
                for (int m = 0; m < 4; ++m) {
                    int row0 = rowbase + mh * 128 + m * 16 + kq * 4;
                    f32x4 v = acc[mh * 4 + m][nh * 2 + n];
#pragma unroll
                    for (int r = 0; r < 4; ++r)
                        C[(size_t)(row0 + r) * Ndim + col] = f32_to_bf16(v[r] + bv);
                }
        }
}

// ---------------- fused banded-conv + LayerNorm ----------------
// Round-3 structure (measured 103.8 us at 34% occupancy) + ONLY the XCD-chunked
// block mapping from round 4 (measured FETCH 255->34 MB). 2048 blocks / 8 XCDs
// = exactly one batch per XCD, consecutive t-tiles adjacent on the same L2.
__global__ __launch_bounds__(256) void conv_ln(
        const u16* __restrict__ h, const float* __restrict__ cwg,
        const float* __restrict__ gamma, const float* __restrict__ beta,
        float* __restrict__ out) {
    const int tid = threadIdx.x;
    const int id0 = blockIdx.x;                      // 2048 blocks
    const int id = (id0 & 7) * 256 + (id0 >> 3);     // bijective: XCD k -> batch k
    const int b = id >> 8;
    const int tb = (id & 255) * 8;

    __shared__ float scw[70];          // scw[i] = cw[i-7], zero-padded (i in [7,62] valid)
    __shared__ float red[4][8][2];
    if (tid < 70) scw[tid] = (tid >= 7 && tid < 63) ? cwg[tid - 7] : 0.f;
    __syncthreads();

    const u16* hb = h + (size_t)b * Lseq * Ndim;
    const int ch = tid * 8;
    float acc[8][8] = {};

    if (tb >= 50) {
        const int lrend = min(62, (Lseq - 1) - (tb - 50));
        const u16* rp = hb + (size_t)(tb - 50) * Ndim + ch;
        for (int lr = 0; lr <= lrend; ++lr) {
            uint4 u = *(const uint4*)rp;
            rp += Ndim;
            float hv[8];
            hv[0] = __builtin_bit_cast(float, u.x << 16);
            hv[1] = __builtin_bit_cast(float, u.x & 0xFFFF0000u);
            hv[2] = __builtin_bit_cast(float, u.y << 16);
            hv[3] = __builtin_bit_cast(float, u.y & 0xFFFF0000u);
            hv[4] = __builtin_bit_cast(float, u.z << 16);
            hv[5] = __builtin_bit_cast(float, u.z & 0xFFFF0000u);
            hv[6] = __builtin_bit_cast(float, u.w << 16);
            hv[7] = __builtin_bit_cast(float, u.w & 0xFFFF0000u);
#pragma unroll
            for (int t2 = 0; t2 < 8; ++t2) {
                float wgt = scw[lr - t2 + 7];
#pragma unroll
                for (int j = 0; j < 8; ++j)
                    acc[t2][j] = fmaf(wgt, hv[j], acc[t2][j]);
            }
        }
    } else {
        const int rmax = tb + 12;
        const u16* rp = hb + ch;
        for (int r = 0; r <= rmax; ++r) {
            uint4 u = *(const uint4*)rp;
            rp += Ndim;
            float hv[8];
            hv[0] = __builtin_bit_cast(float, u.x << 16);
            hv[1] = __builtin_bit_cast(float, u.x & 0xFFFF0000u);
            hv[2] = __builtin_bit_cast(float, u.y << 16);
            hv[3] = __builtin_bit_cast(float, u.y & 0xFFFF0000u);
            hv[4] = __builtin_bit_cast(float, u.z << 16);
            hv[5] = __builtin_bit_cast(float, u.z & 0xFFFF0000u);
            hv[6] = __builtin_bit_cast(float, u.w << 16);
            hv[7] = __builtin_bit_cast(float, u.w & 0xFFFF0000u);
#pragma unroll
            for (int t2 = 0; t2 < 8; ++t2) {
                int t = tb + t2;
                float wgt;
                if (t >= 50) {
                    int wi = r - t + 50;
                    wgt = ((unsigned)wi <= 55u) ? scw[wi + 7] : 0.f;
                } else if (r < t) {
                    wgt = scw[r + 7];
                } else {
                    int d = r - t;
                    wgt = (d <= 5) ? scw[50 + d + 7] : 0.f;
                }
#pragma unroll
                for (int j = 0; j < 8; ++j)
                    acc[t2][j] = fmaf(wgt, hv[j], acc[t2][j]);
            }
        }
    }

    float g[8], be[8];
    *(float4*)&g[0] = *(const float4*)(gamma + ch);
    *(float4*)&g[4] = *(const float4*)(gamma + ch + 4);
    *(float4*)&be[0] = *(const float4*)(beta + ch);
    *(float4*)&be[4] = *(const float4*)(beta + ch + 4);

    float s1v[8], s2v[8];
#pragma unroll
    for (int t2 = 0; t2 < 8; ++t2) {
        float s1 = 0.f, s2 = 0.f;
#pragma unroll
        for (int j = 0; j < 8; ++j) {
            s1 += acc[t2][j];
            s2 += acc[t2][j] * acc[t2][j];
        }
        s1v[t2] = s1;
        s2v[t2] = s2;
    }
#pragma unroll
    for (int off = 32; off; off >>= 1) {
#pragma unroll
        for (int t2 = 0; t2 < 8; ++t2) {
            s1v[t2] += __shfl_down(s1v[t2], off);
            s2v[t2] += __shfl_down(s2v[t2], off);
        }
    }
    const int wv = tid >> 6, lane = tid & 63;
    if (lane == 0) {
#pragma unroll
        for (int t2 = 0; t2 < 8; ++t2) {
            red[wv][t2][0] = s1v[t2];
            red[wv][t2][1] = s2v[t2];
        }
    }
    __syncthreads();
    const float inv = 1.0f / (float)Ndim;
#pragma unroll
    for (int t2 = 0; t2 < 8; ++t2) {
        float S1 = red[0][t2][0] + red[1][t2][0] + red[2][t2][0] + red[3][t2][0];
        float S2 = red[0][t2][1] + red[1][t2][1] + red[2][t2][1] + red[3][t2][1];
        float mu = S1 * inv;
        float var = S2 * inv - mu * mu;
        float rs = rsqrtf(var + 1e-5f);
        size_t base = ((size_t)(b * Lseq + tb + t2)) * Ndim + ch;
        float4 o0, o1;
        o0.x = (acc[t2][0] - mu) * rs * g[0] + be[0];
        o0.y = (acc[t2][1] - mu) * rs * g[1] + be[1];
        o0.z = (acc[t2][2] - mu) * rs * g[2] + be[2];
        o0.w = (acc[t2][3] - mu) * rs * g[3] + be[3];
        o1.x = (acc[t2][4] - mu) * rs * g[4] + be[4];
        o1.y = (acc[t2][5] - mu) * rs * g[5] + be[5];
        o1.z = (acc[t2][6] - mu) * rs * g[6] + be[6];
        o1.w = (acc[t2][7] - mu) * rs * g[7] + be[7];
        *(float4*)(out + base) = o0;
        *(float4*)(out + base + 4) = o1;
    }
}

extern "C" void kernel_launch(void* const* d_in, const int* in_sizes, int n_in,
                              void* d_out, int out_size, void* d_ws, size_t ws_size,
                              hipStream_t stream) {
    const float* x     = (const float*)d_in[0];  // [8,2048,1024]
    const float* W     = (const float*)d_in[1];  // [2048,1024]
    const float* b_lin = (const float*)d_in[2];  // [2048]
    const float* mem_w = (const float*)d_in[3];  // [50,2048]
    const float* la_w  = (const float*)d_in[4];  // [5,2048]
    const float* gamma = (const float*)d_in[5];  // [2048]
    const float* beta  = (const float*)d_in[6];  // [2048]
    float* out = (float*)d_out;

    u16* xb = (u16*)d_ws;                 // 16,777,216 bf16
    u16* wb = xb + (size_t)16777216;      //  2,097,152 bf16
    u16* hb = wb + (size_t)2097152;       // 33,554,432 bf16
    float* cw = (float*)(hb + (size_t)33554432);  // 56 f32

    taps_kernel<<<dim3(56), dim3(256), 0, stream>>>(mem_w, la_w, cw);
    cast_f32_bf16<<<dim3(8192), dim3(256), 0, stream>>>(x, xb, 2097152);
    cast_f32_bf16<<<dim3(1024), dim3(256), 0, stream>>>(W, wb, 262144);
    gemm8<<<dim3(512), dim3(512), 0, stream>>>(xb, wb, b_lin, hb);
    conv_ln<<<dim3(2048), dim3(256), 0, stream>>>(hb, cw, gamma, beta, out);
}